// Round 1
// baseline (4701.693 us; speedup 1.0000x reference)
//
#include <hip/hip_runtime.h>

typedef unsigned short u16;
typedef unsigned int u32;
typedef unsigned long long u64;
typedef float f32x4 __attribute__((ext_vector_type(4)));
typedef short s16x8 __attribute__((ext_vector_type(8)));
typedef int v4i __attribute__((ext_vector_type(4)));

__device__ inline float bf2f(u16 u){ return __uint_as_float(((u32)u) << 16); }
__device__ inline u16 f2bf(float x){
  u32 u = __float_as_uint(x);
  return (u16)((u + 0x7fffu + ((u >> 16) & 1u)) >> 16);
}
__device__ inline u32 pk2(float a, float b){ return (u32)f2bf(a) | ((u32)f2bf(b) << 16); }
__device__ inline float rcpf_(float x){ return __builtin_amdgcn_rcpf(x); }
__device__ inline float sigf(float x){ return rcpf_(1.f + __expf(-x)); }
__device__ inline float tanhf_(float x){
  float xx = fminf(15.f, fmaxf(-15.f, x));
  float e = __expf(2.f * xx);
  return (e - 1.f) * rcpf_(e + 1.f);
}
__device__ inline float ldf(const void* p, size_t i, bool f32){
  return f32 ? ((const float*)p)[i] : bf2f(((const u16*)p)[i]);
}
// load 8 contiguous values as bf16x8 (uint4), converting from f32 if needed
__device__ inline uint4 ld8(const void* base, size_t off, bool f32){
  if (f32){
    const float* p = (const float*)base + off;
    float4 a = *(const float4*)p;
    float4 b = *(const float4*)(p + 4);
    return make_uint4(pk2(a.x,a.y), pk2(a.z,a.w), pk2(b.x,b.y), pk2(b.z,b.w));
  }
  return *(const uint4*)((const u16*)base + off);
}

// ---------------------------------------------------------------------------
// Runtime dtype sniffer: bf16 data -> low u16 of each dword has a sane bf16
// exponent (~N(0,1)); f32 data -> low u16 is mantissa bits (uniform exponent).
// flag = 1 if inputs are float32, 0 if bf16.
// ---------------------------------------------------------------------------
__global__ void sniff_k(const u32* __restrict__ x1w, u32* __restrict__ flag){
  u32 v = x1w[threadIdx.x];
  u32 e = (v >> 7) & 0xffu;
  u64 m = __ballot(e >= 100u && e <= 140u);
  if (threadIdx.x == 0) *flag = (__popcll(m) >= 40) ? 0u : 1u;
}

// ---------------------------------------------------------------------------
// Generic 128x128-tile bf16 MFMA GEMM, C = A * B^T (+bias) with per-mode
// epilogue. MODE 0: XG = x1 @ [w_ih_f;w_ih_b]^T + (b_ih+b_hh), out bf16 s2048
//                  *** stored J-MAJOR within each dir: col = dir*1024+j*4+g ***
//          MODE 1: x2h = X2C @ mlp_mha_w^T + b -> FIN[.,512+n] (bf16, s1024)
//          MODE 2: out = FIN @ mlp_w^T + mlp_b, masked by t<len, N=400
// A external (dtype-flagged) only in MODE 0; B/biases always external.
// ---------------------------------------------------------------------------
template<int MODE>
__global__ __launch_bounds__(256) void gemm_k(
    const void* A, const void* Bm0, const void* Bm1,
    const void* bias0, const void* bias1, const void* bias2, const void* bias3,
    void* Cout, const int* __restrict__ lens, const u32* __restrict__ flag)
{
  constexpr int KACT = (MODE == 2) ? 1024 : 400;
  constexpr int KT   = (MODE == 2) ? 32 : 13;
  constexpr int AS   = (MODE == 0) ? 400 : 1024;   // A row stride (elements)

  const bool f32in = (*flag != 0);
  const bool aF32  = (MODE == 0) && f32in;

  __shared__ alignas(16) u16 Asl[2][128 * 40];
  __shared__ alignas(16) u16 Bsl[2][128 * 40];

  const int tid = threadIdx.x;
  const int m0 = blockIdx.x * 128, n0 = blockIdx.y * 128;
  const int lane = tid & 63, wv = tid >> 6, wm = wv >> 1, wn = wv & 1;

  uint4 ra[2], rb[2];

  auto load_tiles = [&](int kt){
    #pragma unroll
    for (int rep = 0; rep < 2; ++rep){
      int o = rep * 256 + tid;
      int row = o >> 2, oct = o & 3;
      int gc = kt * 32 + oct * 8;
      uint4 va = make_uint4(0,0,0,0), vb = make_uint4(0,0,0,0);
      if (gc < KACT){
        va = ld8(A, (size_t)(m0 + row) * AS + gc, aF32);
        int grow = n0 + row;
        if (MODE == 0){
          const void* bsrc; size_t boff;
          if (grow < 1024){ bsrc = Bm0; boff = (size_t)grow * 400 + gc; }
          else            { bsrc = Bm1; boff = (size_t)(grow - 1024) * 400 + gc; }
          vb = ld8(bsrc, boff, f32in);
        } else if (MODE == 1){
          vb = ld8(Bm0, (size_t)grow * 400 + gc, f32in);
        } else {
          if (grow < 400) vb = ld8(Bm0, (size_t)grow * 1024 + gc, f32in);
        }
      }
      ra[rep] = va; rb[rep] = vb;
    }
  };
  auto store_tiles = [&](int buf){
    #pragma unroll
    for (int rep = 0; rep < 2; ++rep){
      int o = rep * 256 + tid;
      int row = o >> 2, oct = o & 3;
      *(uint4*)(&Asl[buf][row * 40 + oct * 8]) = ra[rep];
      *(uint4*)(&Bsl[buf][row * 40 + oct * 8]) = rb[rep];
    }
  };

  f32x4 acc[4][4];
  #pragma unroll
  for (int mt = 0; mt < 4; ++mt)
    #pragma unroll
    for (int nt = 0; nt < 4; ++nt) acc[mt][nt] = f32x4{0.f,0.f,0.f,0.f};

  load_tiles(0);
  store_tiles(0);
  __syncthreads();

  for (int kt = 0; kt < KT; ++kt){
    if (kt + 1 < KT) load_tiles(kt + 1);
    int buf = kt & 1;
    s16x8 af[4], bfr[4];
    #pragma unroll
    for (int mt = 0; mt < 4; ++mt)
      af[mt] = *(const s16x8*)(&Asl[buf][(wm * 64 + mt * 16 + (lane & 15)) * 40 + (lane >> 4) * 8]);
    #pragma unroll
    for (int nt = 0; nt < 4; ++nt)
      bfr[nt] = *(const s16x8*)(&Bsl[buf][(wn * 64 + nt * 16 + (lane & 15)) * 40 + (lane >> 4) * 8]);
    #pragma unroll
    for (int mt = 0; mt < 4; ++mt)
      #pragma unroll
      for (int nt = 0; nt < 4; ++nt)
        acc[mt][nt] = __builtin_amdgcn_mfma_f32_16x16x32_bf16(af[mt], bfr[nt], acc[mt][nt], 0, 0, 0);
    if (kt + 1 < KT) store_tiles(buf ^ 1);
    __syncthreads();
  }

  #pragma unroll
  for (int nt = 0; nt < 4; ++nt){
    int n = n0 + wn * 64 + nt * 16 + (lane & 15);
    float bs = 0.f;
    if (MODE == 0) bs = (n < 1024) ? (ldf(bias0, n, f32in) + ldf(bias1, n, f32in))
                                   : (ldf(bias2, n - 1024, f32in) + ldf(bias3, n - 1024, f32in));
    if (MODE == 1) bs = ldf(bias0, n, f32in);
    if (MODE == 2) bs = (n < 400) ? ldf(bias0, n, f32in) : 0.f;
    #pragma unroll
    for (int mt = 0; mt < 4; ++mt){
      #pragma unroll
      for (int r = 0; r < 4; ++r){
        int m = m0 + wm * 64 + mt * 16 + (lane >> 4) * 4 + r;
        float v = acc[mt][nt][r] + bs;
        if (MODE == 0){
          // permute columns to j-major within each dir: col = dir*1024 + j*4 + g
          int dn = n >> 10, nl = n & 1023;
          ((u16*)Cout)[(size_t)m * 2048 + (dn << 10) + ((nl & 255) << 2) + (nl >> 8)] = f2bf(v);
        } else if (MODE == 1){
          ((u16*)Cout)[(size_t)m * 1024 + 512 + n] = f2bf(v);
        } else {
          if (n < 400){
            int b = m >> 10, t = m & 1023;
            float vv = (t < lens[b]) ? v : 0.f;
            if (f32in) ((float*)Cout)[(size_t)m * 400 + n] = vv;
            else       ((u16*)Cout)[(size_t)m * 400 + n] = f2bf(vv);
          }
        }
      }
    }
  }
}

// ---------------------------------------------------------------------------
// x2ctx[b,t,e] = mean_s x2[b,t,s,e]  (attention collapses analytically:
// softmax rows sum to 1 -> attn.mean(-1) = 1/S -> w = uniform 1/S).
// Output into FIN cols 0..399 (stride 1024), bf16.
// ---------------------------------------------------------------------------
__global__ __launch_bounds__(256) void ctx_k(const void* __restrict__ x2v,
                                             u16* __restrict__ X2C,
                                             const u32* __restrict__ flag)
{
  const bool f32in = (*flag != 0);
  int gid = blockIdx.x * 256 + threadIdx.x;   // 16384*100 threads, 4 ch each
  int bt = gid / 100, oc = gid - bt * 100;
  float a0=0.f, a1=0.f, a2=0.f, a3=0.f;
  if (f32in){
    const float* p = (const float*)x2v + (size_t)bt * 8000 + oc * 4;
    #pragma unroll
    for (int s = 0; s < 20; ++s){
      float4 v = *(const float4*)(p + (size_t)s * 400);
      a0 += v.x; a1 += v.y; a2 += v.z; a3 += v.w;
    }
  } else {
    const u16* p = (const u16*)x2v + (size_t)bt * 8000 + oc * 4;
    #pragma unroll
    for (int s = 0; s < 20; ++s){
      uint2 v = *(const uint2*)(p + (size_t)s * 400);
      a0 += bf2f((u16)(v.x & 0xffff)); a1 += bf2f((u16)(v.x >> 16));
      a2 += bf2f((u16)(v.y & 0xffff)); a3 += bf2f((u16)(v.y >> 16));
    }
  }
  const float sc = 0.05f;  // 1/20
  *(uint2*)(X2C + (size_t)bt * 1024 + oc * 4) =
      make_uint2(pk2(a0*sc, a1*sc), pk2(a2*sc, a3*sc));
}

// ---------------------------------------------------------------------------
// Bidirectional LSTM recurrence, ONE CU PER DIRECTION (grid = 2 blocks of
// 512 threads). W_hh is quantized to int8 (per-gate absmax scale) and held
// entirely in registers (128 VGPR/thread); h is quantized to int8 (scale
// 1/127) each step. The h handoff between steps is via LDS with a single
// __syncthreads per step (all buffers parity double-buffered) — no cross-CU
// coherent-memory polling at all.
//
// Layout: wave w (of 8) owns gate-rows [w*128, w*128+128) in j-major row
// space ra = 4*j + g. MFMA 16x16x64 i8: A = weights (rows), B = h (cols =
// batch). K-dim is stored in permuted order k' (j = (k'&~31) + (k'&7)*4 +
// ((k'>>3)&3)) applied identically to A-fragments (at quantize time) and to
// the h LDS buffer (at write time), making each lane's 8 h writes one
// contiguous 8-byte store.
// ---------------------------------------------------------------------------
__global__ __launch_bounds__(512, 1) void lstm_k(
    const u16* __restrict__ XG, const void* __restrict__ whhf, const void* __restrict__ whhb,
    const int* __restrict__ seq_lens, u16* __restrict__ HOUT, const u32* __restrict__ flag)
{
  const bool f32in = (*flag != 0);
  const int dir = blockIdx.x;
  const void* Whh = dir ? whhb : whhf;
  const int tid = threadIdx.x;
  const int lane = tid & 63, w = tid >> 6;   // 8 waves
  const int q = lane >> 4, bl = lane & 15;   // q: k-group; bl: batch / A-row-in-tile

  __shared__ alignas(16) signed char h8[2][16][272];   // int8 h, k'-permuted
  __shared__ alignas(16) u16 hbf[2][16][264];          // bf16 h, true-j layout
  __shared__ u32 gmax[4];
  __shared__ float sdeq[4], srq[4];

  // ---- per-gate weight absmax (one-time) ----
  if (tid < 4) gmax[tid] = 0u;
  __syncthreads();
  {
    #pragma unroll 1
    for (int rr = 0; rr < 2; ++rr){
      int r = tid * 2 + rr;              // w_hh row (gate-major, 1024 rows)
      size_t ro = (size_t)r * 256;
      u32 mx = 0u;
      #pragma unroll 4
      for (int cix = 0; cix < 256; ++cix){
        u32 b = __float_as_uint(ldf(Whh, ro + cix, f32in)) & 0x7fffffffu;
        mx = (b > mx) ? b : mx;
      }
      atomicMax(&gmax[r >> 8], mx);
    }
  }
  __syncthreads();
  if (tid < 4){
    float am = __uint_as_float(gmax[tid]);
    srq[tid]  = (am > 1e-20f) ? 127.f / am : 0.f;
    sdeq[tid] = am * (1.f / 16129.f);    // am/127 (w scale) * 1/127 (h scale)
  }
  // zero the t=0 h buffer (parity 1)
  for (int i = tid; i < 1088; i += 512) ((u32*)(&h8[1][0][0]))[i] = 0u;
  __syncthreads();

  const float rs_l = srq[bl & 3];        // quant scale for this lane's A rows
  const float s0 = sdeq[0], s1 = sdeq[1], s2 = sdeq[2], s3 = sdeq[3];

  // ---- quantize + gather W_hh fragments into registers (one-time) ----
  v4i afr[8][4];
  #pragma unroll
  for (int nt = 0; nt < 8; ++nt){
    #pragma unroll
    for (int kt = 0; kt < 4; ++kt){
      int ra = w * 128 + nt * 16 + bl;   // j-major row: ra = 4*j + g
      int d  = ra >> 2, g = ra & 3;
      const size_t rowoff = (size_t)((g << 8) + d) * 256;  // w_hh row g*256+d
      u32 dw0, dw1, dw2, dw3;
      #pragma unroll
      for (int dd = 0; dd < 4; ++dd){
        u32 pk = 0;
        #pragma unroll 1
        for (int bb = 0; bb < 4; ++bb){
          int kp = kt * 64 + q * 16 + dd * 4 + bb;                   // k' index
          int j  = (kp & ~31) + ((kp & 7) << 2) + ((kp >> 3) & 3);   // true j
          float wv = ldf(Whh, rowoff + j, f32in);
          int qv = (int)rintf(wv * rs_l);
          pk |= ((u32)(qv & 0xff)) << (bb * 8);
        }
        if (dd == 0) dw0 = pk; else if (dd == 1) dw1 = pk;
        else if (dd == 2) dw2 = pk; else dw3 = pk;
      }
      afr[nt][kt] = v4i{(int)dw0, (int)dw1, (int)dw2, (int)dw3};
    }
  }

  // per-lane xg addressing (batch = bl), per-half-wave HOUT batch
  const int len_l = seq_lens[bl];
  const int bh = w * 2 + (lane >> 5);
  const int len_h = seq_lens[bh];
  const int cl = (lane & 31) * 8;
  const u16* XGd = XG + ((size_t)dir << 10);
  const int xgc = (w * 32 + q) * 4;      // u16 col base; +nt*16 per nt

  uint2 xr[8], xn[8];
  {
    int r0 = dir ? (len_l - 1) : 0;
    const u16* src = XGd + ((size_t)(bl << 10) + r0) * 2048 + xgc;
    #pragma unroll
    for (int nt = 0; nt < 8; ++nt) xr[nt] = *(const uint2*)(src + nt * 16);
  }
  float c[8];
  #pragma unroll
  for (int nt = 0; nt < 8; ++nt) c[nt] = 0.f;

  #pragma unroll 1
  for (int t = 0; t < 1024; ++t){
    const int p = t & 1;
    // (1) B fragments = h_{t-1} (zeros at t=0)
    v4i bfg[4];
    #pragma unroll
    for (int kt = 0; kt < 4; ++kt)
      bfg[kt] = *(const v4i*)(&h8[p ^ 1][bl][kt * 64 + q * 16]);
    // (2) prefetch next step's xg (register, per-lane scattered global)
    if (t < 1023){
      int tt = t + 1;
      int rt = dir ? ((tt < len_l) ? (len_l - 1 - tt) : tt) : tt;
      const u16* src = XGd + ((size_t)(bl << 10) + rt) * 2048 + xgc;
      #pragma unroll
      for (int nt = 0; nt < 8; ++nt) xn[nt] = *(const uint2*)(src + nt * 16);
    }
    // (3) coalesced HOUT writeback of h_{t-1}
    if (t > 0){
      int tm = t - 1;
      int pos = dir ? ((tm < len_h) ? (len_h - 1 - tm) : tm) : tm;
      uint4 hv = *(const uint4*)(&hbf[p ^ 1][bh][cl]);
      *(uint4*)(HOUT + ((size_t)((bh << 10) + pos)) * 512 + (dir << 8) + cl) = hv;
    }
    // (4) matvec: gates_i32 = Whh_q @ h_q
    v4i acc[8];
    #pragma unroll
    for (int nt = 0; nt < 8; ++nt) acc[nt] = v4i{0, 0, 0, 0};
    #pragma unroll
    for (int kt = 0; kt < 4; ++kt)
      #pragma unroll
      for (int nt = 0; nt < 8; ++nt)
        acc[nt] = __builtin_amdgcn_mfma_i32_16x16x64_i8(afr[nt][kt], bfg[kt], acc[nt], 0, 0, 0);
    // (5) gates + state update + publish h (bf16 true-j, int8 k'-permuted)
    u32 hq0 = 0, hq1 = 0;
    #pragma unroll
    for (int nt = 0; nt < 8; ++nt){
      float xi  = __uint_as_float(xr[nt].x << 16);
      float xf  = __uint_as_float(xr[nt].x & 0xffff0000u);
      float xg_ = __uint_as_float(xr[nt].y << 16);
      float xo  = __uint_as_float(xr[nt].y & 0xffff0000u);
      float gi = fmaf((float)acc[nt][0], s0, xi);
      float gf = fmaf((float)acc[nt][1], s1, xf);
      float gg = fmaf((float)acc[nt][2], s2, xg_);
      float go = fmaf((float)acc[nt][3], s3, xo);
      float cc = sigf(gf) * c[nt] + sigf(gi) * tanhf_(gg);
      c[nt] = cc;
      float h = sigf(go) * tanhf_(cc);
      hbf[p][bl][w * 32 + nt * 4 + q] = f2bf(h);
      int qh = (int)rintf(h * 127.f);
      if (nt < 4) hq0 |= ((u32)(qh & 0xff)) << (nt * 8);
      else        hq1 |= ((u32)(qh & 0xff)) << ((nt - 4) * 8);
    }
    *(uint2*)(&h8[p][bl][w * 32 + q * 8]) = make_uint2(hq0, hq1);
    #pragma unroll
    for (int nt = 0; nt < 8; ++nt) xr[nt] = xn[nt];
    __syncthreads();   // h8[p], hbf[p] complete; next step may read them
  }
  // flush h_{1023} (parity 1)
  {
    int pos = dir ? ((1023 < len_h) ? (len_h - 1024) : 1023) : 1023;
    uint4 hv = *(const uint4*)(&hbf[1][bh][cl]);
    *(uint4*)(HOUT + ((size_t)((bh << 10) + pos)) * 512 + (dir << 8) + cl) = hv;
  }
}

// ---------------------------------------------------------------------------
// cm[b,t,c] = cumsum_t(H_out)/(t+1) -> FIN[.,0:512]. Rows t>=len hold garbage
// relative to ref but are zeroed by the final GEMM's mask.
// ---------------------------------------------------------------------------
__global__ __launch_bounds__(256) void cumsum_k(const u16* __restrict__ HOUT, u16* __restrict__ FIN)
{
  int b = blockIdx.x, cc = blockIdx.y;
  int tid = threadIdx.x;
  int c = tid & 31, seg = tid >> 5;      // 32 channels x 8 time-segments of 128
  int ch = cc * 32 + c;
  __shared__ float ss[8][32];

  size_t base = ((size_t)(b * 1024 + seg * 128)) * 512 + ch;
  float s = 0.f;
  #pragma unroll 8
  for (int i = 0; i < 128; ++i) s += bf2f(HOUT[base + (size_t)i * 512]);
  ss[seg][c] = s;
  __syncthreads();
  if (tid < 32){
    float run = 0.f;
    #pragma unroll
    for (int g = 0; g < 8; ++g){ float v = ss[g][tid]; ss[g][tid] = run; run += v; }
  }
  __syncthreads();
  float run = ss[seg][c];
  size_t ob = ((size_t)(b * 1024 + seg * 128)) * 1024 + cc * 32 + c;
  #pragma unroll 8
  for (int i = 0; i < 128; ++i){
    run += bf2f(HOUT[base + (size_t)i * 512]);
    int t = seg * 128 + i;
    FIN[ob + (size_t)i * 1024] = f2bf(run * rcpf_((float)(t + 1)));
  }
}

// ---------------------------------------------------------------------------
extern "C" void kernel_launch(void* const* d_in, const int* in_sizes, int n_in,
                              void* d_out, int out_size, void* d_ws, size_t ws_size,
                              hipStream_t stream)
{
  (void)in_sizes; (void)n_in; (void)out_size; (void)ws_size;
  const int* lens = (const int*)d_in[2];

  char* ws = (char*)d_ws;
  u16* XG   = (u16*)(ws);                    // 16384 x 2048 bf16 = 64 MiB (j-major per dir)
  u16* FIN  = (u16*)(ws + 67108864);         // 16384 x 1024 bf16 (X2C | cm | x2h)
  u16* HOUT = (u16*)(ws + 100663296);        // 16384 x 512 bf16 = 16 MiB
  u32* FLAG = (u32*)(ws + 117506048);        // dtype flag (1 = f32 inputs)

  // 0. runtime dtype detection
  sniff_k<<<1, 64, 0, stream>>>((const u32*)d_in[0], FLAG);
  // 1. XG = x1 @ [w_ih_f; w_ih_b]^T + (b_ih + b_hh)   (j-major columns)
  gemm_k<0><<<dim3(128, 16), 256, 0, stream>>>(d_in[0], d_in[7], d_in[11],
      d_in[9], d_in[10], d_in[13], d_in[14], XG, nullptr, FLAG);
  // 2. x2ctx = mean_s x2  -> FIN[:,0:400]
  ctx_k<<<6400, 256, 0, stream>>>(d_in[1], FIN, FLAG);
  // 3. x2h = X2C @ mlp_mha_w^T + b  -> FIN[:,512:1024]
  gemm_k<1><<<dim3(128, 4), 256, 0, stream>>>(FIN, d_in[5], nullptr,
      d_in[6], nullptr, nullptr, nullptr, FIN, nullptr, FLAG);
  // 4. bidirectional LSTM recurrence: one CU per direction, int8 W_hh/h
  lstm_k<<<2, 512, 0, stream>>>(XG, d_in[8], d_in[12], lens, HOUT, FLAG);
  // 5. cm -> FIN[:,0:512]
  cumsum_k<<<dim3(16, 16), 256, 0, stream>>>(HOUT, FIN);
  // 6. out = FIN @ mlp_w^T + mlp_b, masked
  gemm_k<2><<<dim3(128, 4), 256, 0, stream>>>(FIN, d_in[15], nullptr,
      d_in[16], nullptr, nullptr, nullptr, d_out, lens, FLAG);
}

// Round 2
// 2668.714 us; speedup vs baseline: 1.7618x; 1.7618x over previous
//
#include <hip/hip_runtime.h>

typedef unsigned short u16;
typedef unsigned int u32;
typedef unsigned long long u64;
typedef float f32x4 __attribute__((ext_vector_type(4)));
typedef short s16x8 __attribute__((ext_vector_type(8)));
typedef int v4i __attribute__((ext_vector_type(4)));

__device__ inline float bf2f(u16 u){ return __uint_as_float(((u32)u) << 16); }
__device__ inline u16 f2bf(float x){
  u32 u = __float_as_uint(x);
  return (u16)((u + 0x7fffu + ((u >> 16) & 1u)) >> 16);
}
__device__ inline u32 pk2(float a, float b){ return (u32)f2bf(a) | ((u32)f2bf(b) << 16); }
__device__ inline float rcpf_(float x){ return __builtin_amdgcn_rcpf(x); }
__device__ inline float sigf(float x){ return rcpf_(1.f + __expf(-x)); }
__device__ inline float tanhf_(float x){
  float xx = fminf(15.f, fmaxf(-15.f, x));
  float e = __expf(2.f * xx);
  return (e - 1.f) * rcpf_(e + 1.f);
}
__device__ inline float ldf(const void* p, size_t i, bool f32){
  return f32 ? ((const float*)p)[i] : bf2f(((const u16*)p)[i]);
}
// load 8 contiguous values as bf16x8 (uint4), converting from f32 if needed
__device__ inline uint4 ld8(const void* base, size_t off, bool f32){
  if (f32){
    const float* p = (const float*)base + off;
    float4 a = *(const float4*)p;
    float4 b = *(const float4*)(p + 4);
    return make_uint4(pk2(a.x,a.y), pk2(a.z,a.w), pk2(b.x,b.y), pk2(b.z,b.w));
  }
  return *(const uint4*)((const u16*)base + off);
}

// ---------------------------------------------------------------------------
// Runtime dtype sniffer: bf16 data -> low u16 of each dword has a sane bf16
// exponent (~N(0,1)); f32 data -> low u16 is mantissa bits (uniform exponent).
// flag = 1 if inputs are float32, 0 if bf16.
// ---------------------------------------------------------------------------
__global__ void sniff_k(const u32* __restrict__ x1w, u32* __restrict__ flag){
  u32 v = x1w[threadIdx.x];
  u32 e = (v >> 7) & 0xffu;
  u64 m = __ballot(e >= 100u && e <= 140u);
  if (threadIdx.x == 0) *flag = (__popcll(m) >= 40) ? 0u : 1u;
}

// ---------------------------------------------------------------------------
// Generic 128x128-tile bf16 MFMA GEMM, C = A * B^T (+bias) with per-mode
// epilogue. MODE 0: XG = x1 @ [w_ih_f;w_ih_b]^T + (b_ih+b_hh), out bf16 s2048
//                  *** stored J-MAJOR within each dir: col = dir*1024+j*4+g ***
//          MODE 1: x2h = X2C @ mlp_mha_w^T + b -> FIN[.,512+n] (bf16, s1024)
//          MODE 2: out = FIN @ mlp_w^T + mlp_b, masked by t<len, N=400
// A external (dtype-flagged) only in MODE 0; B/biases always external.
// ---------------------------------------------------------------------------
template<int MODE>
__global__ __launch_bounds__(256) void gemm_k(
    const void* A, const void* Bm0, const void* Bm1,
    const void* bias0, const void* bias1, const void* bias2, const void* bias3,
    void* Cout, const int* __restrict__ lens, const u32* __restrict__ flag)
{
  constexpr int KACT = (MODE == 2) ? 1024 : 400;
  constexpr int KT   = (MODE == 2) ? 32 : 13;
  constexpr int AS   = (MODE == 0) ? 400 : 1024;   // A row stride (elements)

  const bool f32in = (*flag != 0);
  const bool aF32  = (MODE == 0) && f32in;

  __shared__ alignas(16) u16 Asl[2][128 * 40];
  __shared__ alignas(16) u16 Bsl[2][128 * 40];

  const int tid = threadIdx.x;
  const int m0 = blockIdx.x * 128, n0 = blockIdx.y * 128;
  const int lane = tid & 63, wv = tid >> 6, wm = wv >> 1, wn = wv & 1;

  uint4 ra[2], rb[2];

  auto load_tiles = [&](int kt){
    #pragma unroll
    for (int rep = 0; rep < 2; ++rep){
      int o = rep * 256 + tid;
      int row = o >> 2, oct = o & 3;
      int gc = kt * 32 + oct * 8;
      uint4 va = make_uint4(0,0,0,0), vb = make_uint4(0,0,0,0);
      if (gc < KACT){
        va = ld8(A, (size_t)(m0 + row) * AS + gc, aF32);
        int grow = n0 + row;
        if (MODE == 0){
          const void* bsrc; size_t boff;
          if (grow < 1024){ bsrc = Bm0; boff = (size_t)grow * 400 + gc; }
          else            { bsrc = Bm1; boff = (size_t)(grow - 1024) * 400 + gc; }
          vb = ld8(bsrc, boff, f32in);
        } else if (MODE == 1){
          vb = ld8(Bm0, (size_t)grow * 400 + gc, f32in);
        } else {
          if (grow < 400) vb = ld8(Bm0, (size_t)grow * 1024 + gc, f32in);
        }
      }
      ra[rep] = va; rb[rep] = vb;
    }
  };
  auto store_tiles = [&](int buf){
    #pragma unroll
    for (int rep = 0; rep < 2; ++rep){
      int o = rep * 256 + tid;
      int row = o >> 2, oct = o & 3;
      *(uint4*)(&Asl[buf][row * 40 + oct * 8]) = ra[rep];
      *(uint4*)(&Bsl[buf][row * 40 + oct * 8]) = rb[rep];
    }
  };

  f32x4 acc[4][4];
  #pragma unroll
  for (int mt = 0; mt < 4; ++mt)
    #pragma unroll
    for (int nt = 0; nt < 4; ++nt) acc[mt][nt] = f32x4{0.f,0.f,0.f,0.f};

  load_tiles(0);
  store_tiles(0);
  __syncthreads();

  for (int kt = 0; kt < KT; ++kt){
    if (kt + 1 < KT) load_tiles(kt + 1);
    int buf = kt & 1;
    s16x8 af[4], bfr[4];
    #pragma unroll
    for (int mt = 0; mt < 4; ++mt)
      af[mt] = *(const s16x8*)(&Asl[buf][(wm * 64 + mt * 16 + (lane & 15)) * 40 + (lane >> 4) * 8]);
    #pragma unroll
    for (int nt = 0; nt < 4; ++nt)
      bfr[nt] = *(const s16x8*)(&Bsl[buf][(wn * 64 + nt * 16 + (lane & 15)) * 40 + (lane >> 4) * 8]);
    #pragma unroll
    for (int mt = 0; mt < 4; ++mt)
      #pragma unroll
      for (int nt = 0; nt < 4; ++nt)
        acc[mt][nt] = __builtin_amdgcn_mfma_f32_16x16x32_bf16(af[mt], bfr[nt], acc[mt][nt], 0, 0, 0);
    if (kt + 1 < KT) store_tiles(buf ^ 1);
    __syncthreads();
  }

  #pragma unroll
  for (int nt = 0; nt < 4; ++nt){
    int n = n0 + wn * 64 + nt * 16 + (lane & 15);
    float bs = 0.f;
    if (MODE == 0) bs = (n < 1024) ? (ldf(bias0, n, f32in) + ldf(bias1, n, f32in))
                                   : (ldf(bias2, n - 1024, f32in) + ldf(bias3, n - 1024, f32in));
    if (MODE == 1) bs = ldf(bias0, n, f32in);
    if (MODE == 2) bs = (n < 400) ? ldf(bias0, n, f32in) : 0.f;
    #pragma unroll
    for (int mt = 0; mt < 4; ++mt){
      #pragma unroll
      for (int r = 0; r < 4; ++r){
        int m = m0 + wm * 64 + mt * 16 + (lane >> 4) * 4 + r;
        float v = acc[mt][nt][r] + bs;
        if (MODE == 0){
          // permute columns to j-major within each dir: col = dir*1024 + j*4 + g
          int dn = n >> 10, nl = n & 1023;
          ((u16*)Cout)[(size_t)m * 2048 + (dn << 10) + ((nl & 255) << 2) + (nl >> 8)] = f2bf(v);
        } else if (MODE == 1){
          ((u16*)Cout)[(size_t)m * 1024 + 512 + n] = f2bf(v);
        } else {
          if (n < 400){
            int b = m >> 10, t = m & 1023;
            float vv = (t < lens[b]) ? v : 0.f;
            if (f32in) ((float*)Cout)[(size_t)m * 400 + n] = vv;
            else       ((u16*)Cout)[(size_t)m * 400 + n] = f2bf(vv);
          }
        }
      }
    }
  }
}

// ---------------------------------------------------------------------------
// x2ctx[b,t,e] = mean_s x2[b,t,s,e]  (attention collapses analytically:
// softmax rows sum to 1 -> attn.mean(-1) = 1/S -> w = uniform 1/S).
// Output into FIN cols 0..399 (stride 1024), bf16.
// ---------------------------------------------------------------------------
__global__ __launch_bounds__(256) void ctx_k(const void* __restrict__ x2v,
                                             u16* __restrict__ X2C,
                                             const u32* __restrict__ flag)
{
  const bool f32in = (*flag != 0);
  int gid = blockIdx.x * 256 + threadIdx.x;   // 16384*100 threads, 4 ch each
  int bt = gid / 100, oc = gid - bt * 100;
  float a0=0.f, a1=0.f, a2=0.f, a3=0.f;
  if (f32in){
    const float* p = (const float*)x2v + (size_t)bt * 8000 + oc * 4;
    #pragma unroll
    for (int s = 0; s < 20; ++s){
      float4 v = *(const float4*)(p + (size_t)s * 400);
      a0 += v.x; a1 += v.y; a2 += v.z; a3 += v.w;
    }
  } else {
    const u16* p = (const u16*)x2v + (size_t)bt * 8000 + oc * 4;
    #pragma unroll
    for (int s = 0; s < 20; ++s){
      uint2 v = *(const uint2*)(p + (size_t)s * 400);
      a0 += bf2f((u16)(v.x & 0xffff)); a1 += bf2f((u16)(v.x >> 16));
      a2 += bf2f((u16)(v.y & 0xffff)); a3 += bf2f((u16)(v.y >> 16));
    }
  }
  const float sc = 0.05f;  // 1/20
  *(uint2*)(X2C + (size_t)bt * 1024 + oc * 4) =
      make_uint2(pk2(a0*sc, a1*sc), pk2(a2*sc, a3*sc));
}

// ---------------------------------------------------------------------------
// Bidirectional LSTM recurrence, ONE (batch, dir) PAIR PER CU: grid = 32
// blocks of 512 threads, zero cross-CU communication (batch recurrences are
// independent; W_hh is replicated). W_hh int8 (per-gate absmax scale) lives
// entirely in registers (128 VGPR/thread); h is int8 (scale 1/127) in LDS.
//
// Per step: all 8 waves run the 1024x256 matvec as MFMA i8 16x16x64 with
// B = h broadcast to all 16 columns (1 real column; matrix-pipe issue is the
// wall either way). Wave w's MFMA rows [w*128, w*128+128) are exactly the
// gate quads for j in [w*32, w*32+32), so the gs handoff is WAVE-LOCAL:
// inline lgkmcnt(0) + sched_barrier instead of a block barrier. Gates run on
// lanes 0..31 of each wave (one h output per lane). One __syncthreads per
// step (publishes h8 for the next step's B-fragments).
// ---------------------------------------------------------------------------
__global__ __launch_bounds__(512, 2) void lstm_k(
    const u16* __restrict__ XG, const void* __restrict__ whhf, const void* __restrict__ whhb,
    const int* __restrict__ seq_lens, u16* __restrict__ HOUT, const u32* __restrict__ flag)
{
  const bool f32in = (*flag != 0);
  const int dir = blockIdx.x & 1, batch = blockIdx.x >> 1;
  const void* Whh = dir ? whhb : whhf;
  const int tid = threadIdx.x;
  const int lane = tid & 63, w = tid >> 6;   // 8 waves
  const int q = lane >> 4, bl = lane & 15;   // q: k-group; bl: A-row-in-tile (col junk)

  __shared__ alignas(16) signed char h8[2][256];   // int8 h, double-buffered
  __shared__ alignas(16) float gs[1024];           // gate sums (wave-local slices)
  __shared__ u32 gmax[4];
  __shared__ float sdeq[4], srq[4];

  // ---- per-gate weight absmax (one-time) ----
  if (tid < 4) gmax[tid] = 0u;
  __syncthreads();
  {
    #pragma unroll 1
    for (int rr = 0; rr < 2; ++rr){
      int r = tid * 2 + rr;              // w_hh row (gate-major, 1024 rows)
      size_t ro = (size_t)r * 256;
      u32 mx = 0u;
      #pragma unroll 4
      for (int cix = 0; cix < 256; ++cix){
        u32 b = __float_as_uint(ldf(Whh, ro + cix, f32in)) & 0x7fffffffu;
        mx = (b > mx) ? b : mx;
      }
      atomicMax(&gmax[r >> 8], mx);
    }
  }
  __syncthreads();
  if (tid < 4){
    float am = __uint_as_float(gmax[tid]);
    srq[tid]  = (am > 1e-20f) ? 127.f / am : 0.f;
    sdeq[tid] = am * (1.f / 16129.f);    // am/127 (w scale) * 1/127 (h scale)
  }
  if (tid < 128) ((u32*)(&h8[0][0]))[tid] = 0u;    // zero both h buffers
  __syncthreads();

  const float rs_l = srq[bl & 3];        // gate of row ra = w*128+nt*16+bl is bl&3
  const float s0 = sdeq[0], s1 = sdeq[1], s2 = sdeq[2], s3 = sdeq[3];

  // ---- quantize + gather W_hh fragments into registers (one-time) ----
  // A-row ra = w*128 + nt*16 + bl (j-major: ra = 4*j + g); k index = true j.
  v4i afr[8][4];
  #pragma unroll
  for (int nt = 0; nt < 8; ++nt){
    #pragma unroll
    for (int kt = 0; kt < 4; ++kt){
      int ra = w * 128 + nt * 16 + bl;
      int d  = ra >> 2, g = ra & 3;
      const size_t rowoff = (size_t)((g << 8) + d) * 256;  // w_hh row g*256+d
      u32 dw0, dw1, dw2, dw3;
      #pragma unroll
      for (int dd = 0; dd < 4; ++dd){
        u32 pk = 0;
        #pragma unroll 1
        for (int bb = 0; bb < 4; ++bb){
          int k = kt * 64 + q * 16 + dd * 4 + bb;          // k == hidden j
          float wv = ldf(Whh, rowoff + k, f32in);
          int qv = (int)rintf(wv * rs_l);
          pk |= ((u32)(qv & 0xff)) << (bb * 8);
        }
        if (dd == 0) dw0 = pk; else if (dd == 1) dw1 = pk;
        else if (dd == 2) dw2 = pk; else dw3 = pk;
      }
      afr[nt][kt] = v4i{(int)dw0, (int)dw1, (int)dw2, (int)dw3};
    }
  }

  // gate-lane setup (lanes 0..31 of each wave; j = w*32 + lane)
  const int jj = (w << 5) + (lane & 31);
  const int len = seq_lens[batch];
  const u16* XGcol = XG + (size_t)((dir << 10) + (jj << 2));   // + row*2048
  const size_t rowb = (size_t)(batch << 10);

  uint2 xr = make_uint2(0,0), xn = make_uint2(0,0);
  if (lane < 32){
    int r0 = dir ? (len - 1) : 0;
    int r1 = dir ? (len - 2) : 1;          // len >= 512 so len-2 >= 0
    xr = *(const uint2*)(XGcol + ((rowb + r0) << 11));
    xn = *(const uint2*)(XGcol + ((rowb + r1) << 11));
  }
  float cst = 0.f;

  #pragma unroll 1
  for (int t = 0; t < 1024; ++t){
    const int rp = (t + 1) & 1, wp = t & 1;
    // (1) matvec: all lanes read broadcast h8 -> every B column identical
    v4i bfg[4];
    #pragma unroll
    for (int kt = 0; kt < 4; ++kt)
      bfg[kt] = *(const v4i*)(&h8[rp][(kt << 6) + (q << 4)]);
    v4i acc[8];
    #pragma unroll
    for (int nt = 0; nt < 8; ++nt) acc[nt] = v4i{0, 0, 0, 0};
    #pragma unroll
    for (int kt = 0; kt < 4; ++kt)
      #pragma unroll
      for (int nt = 0; nt < 8; ++nt)
        acc[nt] = __builtin_amdgcn_mfma_i32_16x16x64_i8(afr[nt][kt], bfg[kt], acc[nt], 0, 0, 0);
    // (2) wave-local gs handoff: lane (q, bl=0) reg r holds row w*128+nt*16+q*4+r
    if (bl == 0){
      #pragma unroll
      for (int nt = 0; nt < 8; ++nt)
        *(float4*)(&gs[(w << 7) + (nt << 4) + (q << 2)]) =
            make_float4((float)acc[nt][0], (float)acc[nt][1],
                        (float)acc[nt][2], (float)acc[nt][3]);
    }
    asm volatile("s_waitcnt lgkmcnt(0)" ::: "memory");
    __builtin_amdgcn_sched_barrier(0);
    // (3) gates: lanes 0..31, one hidden unit each (reads own wave's gs slice)
    if (lane < 32){
      float4 g4 = *(const float4*)(&gs[jj << 2]);
      float xi  = __uint_as_float(xr.x << 16);
      float xf  = __uint_as_float(xr.x & 0xffff0000u);
      float xg_ = __uint_as_float(xr.y << 16);
      float xo  = __uint_as_float(xr.y & 0xffff0000u);
      float gi = fmaf(g4.x, s0, xi);
      float gf = fmaf(g4.y, s1, xf);
      float gg = fmaf(g4.z, s2, xg_);
      float go = fmaf(g4.w, s3, xo);
      cst = sigf(gf) * cst + sigf(gi) * tanhf_(gg);
      float h = sigf(go) * tanhf_(cst);
      int pos = dir ? ((t < len) ? (len - 1 - t) : t) : t;
      HOUT[((rowb + pos) << 9) + (dir << 8) + jj] = f2bf(h);
      h8[wp][jj] = (signed char)(int)rintf(h * 127.f);
      xr = xn;
      int t2 = t + 2;
      if (t2 < 1024){
        int rt = dir ? ((t2 < len) ? (len - 1 - t2) : t2) : t2;
        xn = *(const uint2*)(XGcol + ((rowb + rt) << 11));
      }
    }
    __syncthreads();   // h8[wp] complete for next step's B-fragments
  }
}

// ---------------------------------------------------------------------------
// cm[b,t,c] = cumsum_t(H_out)/(t+1) -> FIN[.,0:512]. Rows t>=len hold garbage
// relative to ref but are zeroed by the final GEMM's mask.
// ---------------------------------------------------------------------------
__global__ __launch_bounds__(256) void cumsum_k(const u16* __restrict__ HOUT, u16* __restrict__ FIN)
{
  int b = blockIdx.x, cc = blockIdx.y;
  int tid = threadIdx.x;
  int c = tid & 31, seg = tid >> 5;      // 32 channels x 8 time-segments of 128
  int ch = cc * 32 + c;
  __shared__ float ss[8][32];

  size_t base = ((size_t)(b * 1024 + seg * 128)) * 512 + ch;
  float s = 0.f;
  #pragma unroll 8
  for (int i = 0; i < 128; ++i) s += bf2f(HOUT[base + (size_t)i * 512]);
  ss[seg][c] = s;
  __syncthreads();
  if (tid < 32){
    float run = 0.f;
    #pragma unroll
    for (int g = 0; g < 8; ++g){ float v = ss[g][tid]; ss[g][tid] = run; run += v; }
  }
  __syncthreads();
  float run = ss[seg][c];
  size_t ob = ((size_t)(b * 1024 + seg * 128)) * 1024 + cc * 32 + c;
  #pragma unroll 8
  for (int i = 0; i < 128; ++i){
    run += bf2f(HOUT[base + (size_t)i * 512]);
    int t = seg * 128 + i;
    FIN[ob + (size_t)i * 1024] = f2bf(run * rcpf_((float)(t + 1)));
  }
}

// ---------------------------------------------------------------------------
extern "C" void kernel_launch(void* const* d_in, const int* in_sizes, int n_in,
                              void* d_out, int out_size, void* d_ws, size_t ws_size,
                              hipStream_t stream)
{
  (void)in_sizes; (void)n_in; (void)out_size; (void)ws_size;
  const int* lens = (const int*)d_in[2];

  char* ws = (char*)d_ws;
  u16* XG   = (u16*)(ws);                    // 16384 x 2048 bf16 = 64 MiB (j-major per dir)
  u16* FIN  = (u16*)(ws + 67108864);         // 16384 x 1024 bf16 (X2C | cm | x2h)
  u16* HOUT = (u16*)(ws + 100663296);        // 16384 x 512 bf16 = 16 MiB
  u32* FLAG = (u32*)(ws + 117506048);        // dtype flag (1 = f32 inputs)

  // 0. runtime dtype detection
  sniff_k<<<1, 64, 0, stream>>>((const u32*)d_in[0], FLAG);
  // 1. XG = x1 @ [w_ih_f; w_ih_b]^T + (b_ih + b_hh)   (j-major columns)
  gemm_k<0><<<dim3(128, 16), 256, 0, stream>>>(d_in[0], d_in[7], d_in[11],
      d_in[9], d_in[10], d_in[13], d_in[14], XG, nullptr, FLAG);
  // 2. x2ctx = mean_s x2  -> FIN[:,0:400]
  ctx_k<<<6400, 256, 0, stream>>>(d_in[1], FIN, FLAG);
  // 3. x2h = X2C @ mlp_mha_w^T + b  -> FIN[:,512:1024]
  gemm_k<1><<<dim3(128, 4), 256, 0, stream>>>(FIN, d_in[5], nullptr,
      d_in[6], nullptr, nullptr, nullptr, FIN, nullptr, FLAG);
  // 4. bidirectional LSTM recurrence: one (batch,dir) per CU, int8 W_hh/h
  lstm_k<<<32, 512, 0, stream>>>(XG, d_in[8], d_in[12], lens, HOUT, FLAG);
  // 5. cm -> FIN[:,0:512]
  cumsum_k<<<dim3(16, 16), 256, 0, stream>>>(HOUT, FIN);
  // 6. out = FIN @ mlp_w^T + mlp_b, masked
  gemm_k<2><<<dim3(128, 4), 256, 0, stream>>>(FIN, d_in[15], nullptr,
      d_in[16], nullptr, nullptr, nullptr, d_out, lens, FLAG);
}